// Round 11
// baseline (258.746 us; speedup 1.0000x reference)
//
#include <hip/hip_runtime.h>
#include <hip/hip_bf16.h>

// Attention forward, MI355X (gfx950). fp32 in/out, bf16 MFMA internally.
// ws (56 MB): wqkv_b[3072x1024 bf16] | wo_b[1024x1024 bf16] | QKV[8192x3072 bf16]
// xb (bf16 x) lives in d_out's first 16 MB (dead before out-proj writes).
// Dispatches: 1 fused convert; QKV GEMM (gemm8p); flash; out-proj GEMM (gemm2p).
// MFMA layouts (verified m89/m74):
//   A-frag: A[m=lane&15][k=(lane>>4)*8+j]; B-frag: B[n=lane&15][k=...]
//   C/D:    col=lane&15, row=(lane>>4)*4+reg
//
// Round-8:  both-sides LDS swizzles in flash. Conflicts 1.62e7->6.5e6, dur flat.
// Round-9:  lgkm-only barrier in flash. 163->157 us.
// Round-10: K LDS-staged + XCD grouping in flash. FETCH 240->38 MB, 157->89.6.
// Round-11: GEMM XCD remap + BK=64 swizzled staging + fused converts. 280->262.
// Round-12: fused pair p-loop: per-CU np imbalance -> 105 us. REVERTED.
// Round-13: ones-MFMA l-sum + setprio: flash 86.3, VGPR 84.
// Round-14: gemm3 QKV (128x256 3-buf counted vmcnt): total 251.0 (best).
// Round-15: gemm2p both GEMMs: 253.3 (~noise). GEMM coarse variants plateau
//           at ~650 TF regardless of tile/buffering.
// Round-16: flash 32q/wave @ grid 512: occupancy 24->11 -> 132 us. REVERTED.
// Round-17: re-anchor best state: 253.8 (noise band of 251.0).
// Round-18 (this): QKV -> gemm8p: SAME 3-buffer rotation + prologue +
//   per-tile vmcnt(6) (all correctness-critical sync identical to the
//   validated gemm3), but each K-tile's compute split into 4 FINE phases
//   over C-quadrants: {ds_read quad frags | stage | barrier | lgkm0+schedbar
//   | setprio + 8 MFMA}. Catalog: T2/T5 gate on the fine phase structure
//   (m230b), not tile size; coarse 2-phase hides them (m233). 8 waves kept
//   (m232: 4-wave 8ph not reproduced).

typedef short short8 __attribute__((ext_vector_type(8)));
typedef float f32x4 __attribute__((ext_vector_type(4)));

#define MFMA16(a, b, c) __builtin_amdgcn_mfma_f32_16x16x32_bf16((a), (b), (c), 0, 0, 0)

static __device__ __forceinline__ ushort f2bf(float f) {
  union { __hip_bfloat16 h; ushort u; } cv;
  cv.h = __float2bfloat16(f);
  return cv.u;
}

static __device__ __forceinline__ float fexp2(float x) {
#if __has_builtin(__builtin_amdgcn_exp2f)
  return __builtin_amdgcn_exp2f(x);
#else
  return __expf(x * 0.69314718056f);
#endif
}

// Barrier WITHOUT any vmcnt drain: LDS writes visible, globals keep flying.
static __device__ __forceinline__ void block_sync_lds() {
  asm volatile("s_waitcnt lgkmcnt(0)" ::: "memory");
  __builtin_amdgcn_s_barrier();
  __builtin_amdgcn_sched_barrier(0);
}

// Barrier that ALSO waits outstanding globals (global_load_lds visibility).
static __device__ __forceinline__ void block_sync_full() {
  asm volatile("s_waitcnt vmcnt(0) lgkmcnt(0)" ::: "memory");
  __builtin_amdgcn_s_barrier();
  __builtin_amdgcn_sched_barrier(0);
}

static __device__ __forceinline__ void store_out(float* p, float v) { *p = v; }
static __device__ __forceinline__ void store_out(__hip_bfloat16* p, float v) {
  *p = __float2bfloat16(v);
}

// One fused convert: wq|wk|wv -> wqkv_b rows, wo -> wo_b, x -> xb.
__global__ __launch_bounds__(256) void convert_all_kernel(
    const float* __restrict__ wq, const float* __restrict__ wk,
    const float* __restrict__ wv, const float* __restrict__ wo,
    const float* __restrict__ x, ushort* __restrict__ wqkv,
    ushort* __restrict__ wob, ushort* __restrict__ xb) {
  constexpr int W4 = 262144;           // (1024*1024)/4
  constexpr size_t WSZ = (size_t)1024 * 1024;
  const int i = blockIdx.x * blockDim.x + threadIdx.x;
  const float* src;
  ushort* dst;
  int j;
  if (i < 2 * W4) {
    if (i < W4)      { src = wq; dst = wqkv;           j = i; }
    else             { src = wk; dst = wqkv + WSZ;     j = i - W4; }
  } else if (i < 4 * W4) {
    if (i < 3 * W4)  { src = wv; dst = wqkv + 2 * WSZ; j = i - 2 * W4; }
    else             { src = wo; dst = wob;            j = i - 3 * W4; }
  } else {
    src = x; dst = xb; j = i - 4 * W4;
  }
  const float4 v = ((const float4*)src)[j];
  ushort4 o;
  o.x = f2bf(v.x); o.y = f2bf(v.y); o.z = f2bf(v.z); o.w = f2bf(v.w);
  ((ushort4*)dst)[j] = o;
}

// ---------------- 2-buffer pipelined 128x128 GEMM (gemm2p, R15) ----------
// C[M,N] = A[M,K](bf16) * B[N,K]^T(bf16), OUT_T out. BK=64, 4 waves,
// wave tile 64x64, 2 LDS buffers (64 KB -> 2 blocks/CU). Counted vmcnt.
template <typename OUT_T>
__global__ __launch_bounds__(256, 2) void gemm_kernel(
    const ushort* __restrict__ A, int lda, const ushort* __restrict__ B, int ldb,
    OUT_T* __restrict__ C, int ldc, int K, int cpx) {
  __shared__ __align__(16) ushort As[2][128 * 64];
  __shared__ __align__(16) ushort Bs[2][128 * 64];
  const int tid = threadIdx.x;
  const int wave = tid >> 6, lane = tid & 63;
  const int lm = lane & 15, quad = lane >> 4;

  const int id = blockIdx.x;
  const int local = id >> 3;
  const int nt = (id & 7) * cpx + local % cpx;
  const int mt = local / cpx;
  const size_t m0 = (size_t)mt * 128;
  const size_t n0 = (size_t)nt * 128;

  const int rl = lane >> 3;        // row within 8-row staging chunk
  const int cs = (lane & 7) ^ rl;  // pre-swizzled source col-chunk
  const int fsw = lm & 7;          // fragment read swizzle key
  const int wm = (wave >> 1) * 64, wn = (wave & 1) * 64;
  const int T = K >> 6;

#pragma unroll
  for (int j = 0; j < 4; ++j) {
    const int ch = wave * 4 + j;
    __builtin_amdgcn_global_load_lds(
        (const __attribute__((address_space(1))) void*)(B + (n0 + ch * 8 + rl) * (size_t)ldb + cs * 8),
        (__attribute__((address_space(3))) void*)(Bs[0] + ch * 512), 16, 0, 0);
    __builtin_amdgcn_global_load_lds(
        (const __attribute__((address_space(1))) void*)(A + (m0 + ch * 8 + rl) * (size_t)lda + cs * 8),
        (__attribute__((address_space(3))) void*)(As[0] + ch * 512), 16, 0, 0);
  }

  f32x4 acc[4][4] = {};
  for (int t = 0; t < T; ++t) {
    const int cur = t & 1;
    if (t + 1 < T) {
      const int k0 = (t + 1) << 6;
      ushort* an = As[cur ^ 1];
      ushort* bn = Bs[cur ^ 1];
#pragma unroll
      for (int j = 0; j < 4; ++j) {
        const int ch = wave * 4 + j;
        __builtin_amdgcn_global_load_lds(
            (const __attribute__((address_space(1))) void*)(B + (n0 + ch * 8 + rl) * (size_t)ldb + k0 + cs * 8),
            (__attribute__((address_space(3))) void*)(bn + ch * 512), 16, 0, 0);
        __builtin_amdgcn_global_load_lds(
            (const __attribute__((address_space(1))) void*)(A + (m0 + ch * 8 + rl) * (size_t)lda + k0 + cs * 8),
            (__attribute__((address_space(3))) void*)(an + ch * 512), 16, 0, 0);
      }
      asm volatile("s_waitcnt vmcnt(8)" ::: "memory");
    } else {
      asm volatile("s_waitcnt vmcnt(0)" ::: "memory");
    }
    __builtin_amdgcn_s_barrier();       // barrier1: tile t visible to all
    __builtin_amdgcn_sched_barrier(0);

    short8 a[4][2], b[4][2];
    const ushort* ab = As[cur];
    const ushort* bb = Bs[cur];
#pragma unroll
    for (int i = 0; i < 4; ++i) {
      const ushort* ar = ab + (wm + i * 16 + lm) * 64;
      const ushort* br = bb + (wn + i * 16 + lm) * 64;
#pragma unroll
      for (int ks = 0; ks < 2; ++ks) {
        const int off = (((ks * 4 + quad) ^ fsw) & 7) << 3;
        a[i][ks] = *(const short8*)(ar + off);
        b[i][ks] = *(const short8*)(br + off);
      }
    }
    asm volatile("s_waitcnt lgkmcnt(0)" ::: "memory");
    __builtin_amdgcn_s_barrier();       // barrier2: all reads done
    __builtin_amdgcn_sched_barrier(0);

    __builtin_amdgcn_s_setprio(1);
#pragma unroll
    for (int i = 0; i < 4; ++i)
#pragma unroll
      for (int j = 0; j < 4; ++j)
#pragma unroll
        for (int ks = 0; ks < 2; ++ks)
          acc[i][j] = MFMA16(a[i][ks], b[j][ks], acc[i][j]);
    __builtin_amdgcn_s_setprio(0);
  }

  const int rq = quad * 4;
#pragma unroll
  for (int i = 0; i < 4; ++i)
#pragma unroll
    for (int j = 0; j < 4; ++j)
#pragma unroll
      for (int r = 0; r < 4; ++r)
        store_out(&C[(m0 + wm + i * 16 + rq + r) * (size_t)ldc + n0 + wn + j * 16 + lm],
                  acc[i][j][r]);
}

// ---------------- 128M x 256N 3-buffer FINE-PHASE GEMM (gemm8p) ----------
// Staging helper (identical addressing to validated gemm3): part0 = A rows
// 0..127 (2 loads) + B rows 0..127 (2); part1 = B rows 128..255 (2).
// Pre-swizzled source (rule 21): element (r, chunk c) -> phys chunk c^(r&7).
static __device__ __forceinline__ void stage_part(
    const ushort* __restrict__ Ab, int lda, const ushort* __restrict__ Bb,
    int ldb, int k0, ushort* abuf, ushort* bbuf, int wave, int lane, int part) {
  const int rl = lane >> 3, c8 = lane & 7;
  const int cs = c8 ^ rl;
  if (part == 0) {
#pragma unroll
    for (int i = 0; i < 2; ++i) {
      const int r = i * 64 + wave * 8 + rl;
      __builtin_amdgcn_global_load_lds(
          (const __attribute__((address_space(1))) void*)(Ab + (size_t)r * lda + k0 + cs * 8),
          (__attribute__((address_space(3))) void*)(abuf + (i * 8 + wave) * 512), 16, 0, 0);
    }
#pragma unroll
    for (int i = 0; i < 2; ++i) {
      const int r = i * 64 + wave * 8 + rl;
      __builtin_amdgcn_global_load_lds(
          (const __attribute__((address_space(1))) void*)(Bb + (size_t)r * ldb + k0 + cs * 8),
          (__attribute__((address_space(3))) void*)(bbuf + (i * 8 + wave) * 512), 16, 0, 0);
    }
  } else {
#pragma unroll
    for (int i = 2; i < 4; ++i) {
      const int r = i * 64 + wave * 8 + rl;
      __builtin_amdgcn_global_load_lds(
          (const __attribute__((address_space(1))) void*)(Bb + (size_t)r * ldb + k0 + cs * 8),
          (__attribute__((address_space(3))) void*)(bbuf + (i * 8 + wave) * 512), 16, 0, 0);
    }
  }
}

// Fine-phase barrier: lockstep + make this phase's ds_reads complete.
static __device__ __forceinline__ void phase_sync() {
  __builtin_amdgcn_s_barrier();
  asm volatile("s_waitcnt lgkmcnt(0)" ::: "memory");
  __builtin_amdgcn_sched_barrier(0);
}

// 512 threads = 8 waves (2M x 4N), wave tile 64x64. 3 LDS buffers (144 KB):
// stage t+2 while computing t (buf last read in tile t-1) -> overwrite-race
// impossible. Per-tile correctness sync: own vmcnt(6) + barrier (t+1 landed,
// t+2's 6 loads stay in flight) — identical to validated gemm3.
// NEW: compute split into 4 fine phases per tile over C-quadrants; each
// phase = {ds_read quad frags | stage issue | barrier+lgkm0 | setprio +
// 8 MFMA}. A/B frag registers live exactly two phases each.
template <typename OUT_T>
__global__ __launch_bounds__(512, 2) void gemm8p_kernel(
    const ushort* __restrict__ A, int lda, const ushort* __restrict__ B, int ldb,
    OUT_T* __restrict__ C, int ldc, int K) {
  __shared__ __align__(16) ushort As[3][128 * 64];
  __shared__ __align__(16) ushort Bs[3][256 * 64];

  const int tid = threadIdx.x;
  const int wave = tid >> 6, lane = tid & 63;
  const int lm = lane & 15, quad = lane >> 4;
  const int wm = wave >> 2, wn = wave & 3;

  const int id = blockIdx.x;
  const int mt = (id & 7) * 8 + ((id >> 3) & 7);
  const int nt = id >> 6;
  const size_t m0 = (size_t)mt * 128;
  const size_t n0 = (size_t)nt * 256;

  const ushort* Abase = A + m0 * (size_t)lda;
  const ushort* Bbase = B + n0 * (size_t)ldb;
  const int fsw = lm & 7;
  const int T = K >> 6;

  // prologue: stage tiles 0 and 1 (12 loads), wait tile 0 (6 newest flying)
  stage_part(Abase, lda, Bbase, ldb, 0, As[0], Bs[0], wave, lane, 0);
  stage_part(Abase, lda, Bbase, ldb, 0, As[0], Bs[0], wave, lane, 1);
  stage_part(Abase, lda, Bbase, ldb, 64, As[1], Bs[1], wave, lane, 0);
  stage_part(Abase, lda, Bbase, ldb, 64, As[1], Bs[1], wave, lane, 1);
  asm volatile("s_waitcnt vmcnt(6)" ::: "memory");
  __builtin_amdgcn_s_barrier();
  __builtin_amdgcn_sched_barrier(0);

  f32x4 acc[4][4] = {};
  int bt = 0, bs = 2;  // buf of tile t / of tile t+2
  for (int t = 0; t < T; ++t) {
    const ushort* ab = As[bt];
    const ushort* bb = Bs[bt];
    const bool pre = (t + 2 < T);
    const int kp = (t + 2) << 6;

    short8 a01[2][2], a23[2][2], b01[2][2], b23[2][2];

    // ---- P0: read A mf0,1 + B nf0,1; stage part0; MFMA quad (01x01) ----
#pragma unroll
    for (int f = 0; f < 2; ++f) {
      const ushort* ar = ab + (wm * 64 + f * 16 + lm) * 64;
      const ushort* br = bb + (wn * 64 + f * 16 + lm) * 64;
#pragma unroll
      for (int ks = 0; ks < 2; ++ks) {
        const int off = (((ks * 4 + quad) ^ fsw) & 7) << 3;
        a01[f][ks] = *(const short8*)(ar + off);
        b01[f][ks] = *(const short8*)(br + off);
      }
    }
    if (pre) stage_part(Abase, lda, Bbase, ldb, kp, As[bs], Bs[bs], wave, lane, 0);
    phase_sync();
    __builtin_amdgcn_s_setprio(1);
#pragma unroll
    for (int mf = 0; mf < 2; ++mf)
#pragma unroll
      for (int nf = 0; nf < 2; ++nf)
#pragma unroll
        for (int ks = 0; ks < 2; ++ks)
          acc[mf][nf] = MFMA16(a01[mf][ks], b01[nf][ks], acc[mf][nf]);
    __builtin_amdgcn_s_setprio(0);

    // ---- P1: read B nf2,3; MFMA quad (01x23) ----
#pragma unroll
    for (int f = 0; f < 2; ++f) {
      const ushort* br = bb + (wn * 64 + (f + 2) * 16 + lm) * 64;
#pragma unroll
      for (int ks = 0; ks < 2; ++ks)
        b23[f][ks] = *(const short8*)(br + ((((ks * 4 + quad) ^ fsw) & 7) << 3));
    }
    phase_sync();
    __builtin_amdgcn_s_setprio(1);
#pragma unroll
    for (int mf = 0; mf < 2; ++mf)
#pragma unroll
      for (int nf = 0; nf < 2; ++nf)
#pragma unroll
        for (int ks = 0; ks < 2; ++ks)
          acc[mf][nf + 2] = MFMA16(a01[mf][ks], b23[nf][ks], acc[mf][nf + 2]);
    __builtin_amdgcn_s_setprio(0);

    // ---- P2: read A mf2,3; stage part1; MFMA quad (23x01) ----
#pragma unroll
    for (int f = 0; f < 2; ++f) {
      const ushort* ar = ab + (wm * 64 + (f + 2) * 16 + lm) * 64;
#pragma unroll
      for (int ks = 0; ks < 2; ++ks)
        a23[f][ks] = *(const short8*)(ar + ((((ks * 4 + quad) ^ fsw) & 7) << 3));
    }
    if (pre) stage_part(Abase, lda, Bbase, ldb, kp, As[bs], Bs[bs], wave, lane, 1);
    phase_sync();
    __builtin_amdgcn_s_setprio(1);
#pragma unroll
    for (int mf = 0; mf < 2; ++mf)
#pragma unroll
      for (int nf = 0; nf < 2; ++nf)
#pragma unroll
        for (int ks = 0; ks < 2; ++ks)
          acc[mf + 2][nf] = MFMA16(a23[mf][ks], b01[nf][ks], acc[mf + 2][nf]);
    __builtin_amdgcn_s_setprio(0);

    // ---- P3: MFMA quad (23x23) (all frags already in regs) ----
    __builtin_amdgcn_s_barrier();
    __builtin_amdgcn_sched_barrier(0);
    __builtin_amdgcn_s_setprio(1);
#pragma unroll
    for (int mf = 0; mf < 2; ++mf)
#pragma unroll
      for (int nf = 0; nf < 2; ++nf)
#pragma unroll
        for (int ks = 0; ks < 2; ++ks)
          acc[mf + 2][nf + 2] = MFMA16(a23[mf][ks], b23[nf][ks], acc[mf + 2][nf + 2]);
    __builtin_amdgcn_s_setprio(0);

    // ---- tile boundary: ensure tile t+1 landed; keep t+2's loads flying --
    if (pre) asm volatile("s_waitcnt vmcnt(6)" ::: "memory");
    else     asm volatile("s_waitcnt vmcnt(0)" ::: "memory");
    __builtin_amdgcn_s_barrier();
    __builtin_amdgcn_sched_barrier(0);

    bt = (bt == 2) ? 0 : bt + 1;
    bs = (bs == 2) ? 0 : bs + 1;
  }

  // epilogue: C write (same C/D mapping as gemm_kernel)
#pragma unroll
  for (int mf = 0; mf < 4; ++mf)
#pragma unroll
    for (int nf = 0; nf < 4; ++nf)
#pragma unroll
      for (int r = 0; r < 4; ++r)
        store_out(&C[(m0 + wm * 64 + mf * 16 + quad * 4 + r) * (size_t)ldc +
                     n0 + wn * 64 + nf * 16 + lm],
                  acc[mf][nf][r]);
}

// Swizzled V^T LDS write: 8 cols starting at h0 for row p.
// Element (p, h) lives at h*64 + (((p>>3) ^ (h>>3) ^ (h&7)) & 7)*8 + (p&7).
static __device__ __forceinline__ void vt_write8(ushort* vtbuf, int h0, int hsw,
                                                 int p, const short8& v) {
  const int pc = (p >> 3) ^ hsw;
  ushort* row = vtbuf + h0 * 64 + (p & 7);
#pragma unroll
  for (int u = 0; u < 8; ++u)
    row[u * 64 + (((pc ^ u) & 7) << 3)] = ((const ushort*)&v)[u];
}

// Stage a 64x64 bf16 K tile into kbuf via global_load_lds (rule 21).
static __device__ __forceinline__ void stage_k(const ushort* kglob, int pbase,
                                               ushort* kbuf, int wave, int lane) {
  const int rl = lane >> 3;
  const int c = (lane & 7) ^ rl;
#pragma unroll
  for (int j = 0; j < 2; ++j) {
    const int ch = wave * 2 + j;
    const ushort* src = kglob + (size_t)(pbase + ch * 8 + rl) * 3072 + c * 8;
    __builtin_amdgcn_global_load_lds(
        (const __attribute__((address_space(1))) void*)src,
        (__attribute__((address_space(3))) void*)(kbuf + ch * 512), 16, 0, 0);
  }
}

// Flash causal attention (R13 structure, verified 86.3 us — converged).
__global__ __launch_bounds__(256) void flash4_kernel(ushort* __restrict__ QKV) {
  constexpr int LD = 3072;
  __shared__ __align__(16) ushort vt[2][64 * 64];
  __shared__ __align__(16) ushort kt[2][64 * 64];
  __shared__ __align__(16) ushort pbuf[4][16 * 64];

  const int id = blockIdx.x;
  const int g = (id & 7) * 8 + ((id >> 3) & 7);  // (b,head) group, XCD-local
  const int m = id >> 6;                          // q-pair index 0..15
  const int head = g & 15;
  const int b = g >> 4;

  const int tid = threadIdx.x;
  const int wave = tid >> 6, lane = tid & 63;
  const int lm = lane & 15, quad = lane >> 4;

  const size_t qcol = (size_t)b * 2048 * LD + head * 64;
  const size_t vcol = qcol + 2048;
  const ushort* kglob = QKV + qcol + 1024;

  const int h0 = (tid & 7) * 8;
  const int hsw = tid & 7;
  const int plb = tid >> 3;
  const int psw = lm & 7;
  const int ksw = lm & 7;

  constexpr float CSC = 0.180336880f;  // log2(e)/8
  const short8 vone = {0x3F80, 0x3F80, 0x3F80, 0x3F80,
                       0x3F80, 0x3F80, 0x3F80, 0x3F80};  // bf16 1.0 x8

  for (int pass = 0; pass < 2; ++pass) {
    const int qbi = pass ? 31 - m : m;
    const int qrow = qbi * 64 + wave * 16;
    const int qg = qrow + lm;
    const int nt = qbi + 1;

    const ushort* qp = QKV + qcol + (size_t)(qrow + lm) * LD;
    short8 qa0 = *(const short8*)(qp + quad * 8);
    short8 qa1 = *(const short8*)(qp + 32 + quad * 8);

    f32x4 accz[4] = {};
    f32x4 lacc = {};

    block_sync_lds();

    stage_k(kglob, 0, kt[0], wave, lane);
#pragma unroll
    for (int rr = 0; rr < 2; ++rr) {
      const int p = plb + rr * 32;
      short8 v = *(const short8*)(QKV + vcol + (size_t)p * LD + h0);
      vt_write8(vt[0], h0, hsw, p, v);
    }

    for (int it = 0; it < nt; ++it) {
      const int p0 = it * 64;
      block_sync_full();

      short8 ka[4], kb[4];
      const ushort* kbuf = kt[it & 1];
#pragma unroll
      for (int s = 0; s < 4; ++s) {
        const ushort* kr = kbuf + (s * 16 + lm) * 64;
        ka[s] = *(const short8*)(kr + (((quad ^ ksw) & 7) << 3));
        kb[s] = *(const short8*)(kr + ((((quad + 4) ^ ksw) & 7) << 3));
      }

      const bool more = (it + 1 < nt);
      short8 nv0, nv1;
      if (more) {
        nv0 = *(const short8*)(QKV + vcol + (size_t)(p0 + 64 + plb) * LD + h0);
        nv1 = *(const short8*)(QKV + vcol + (size_t)(p0 + 96 + plb) * LD + h0);
        stage_k(kglob, p0 + 64, kt[(it + 1) & 1], wave, lane);
      }

      f32x4 t4[4];
      __builtin_amdgcn_s_setprio(1);
#pragma unroll
      for (int s = 0; s < 4; ++s) {
        f32x4 t = {0.f, 0.f, 0.f, 0.f};
        t = MFMA16(ka[s], qa0, t);
        t = MFMA16(kb[s], qa1, t);
        t4[s] = t;
      }
      __builtin_amdgcn_s_setprio(0);

      float ps[4][4];
      if (it != nt - 1) {
#pragma unroll
        for (int s = 0; s < 4; ++s)
#pragma unroll
          for (int r = 0; r < 4; ++r)
            ps[s][r] = fexp2(t4[s][r] * CSC);
      } else {
#pragma unroll
        for (int s = 0; s < 4; ++s)
#pragma unroll
          for (int r = 0; r < 4; ++r) {
            const int pg = p0 + s * 16 + quad * 4 + r;
            const float e = fexp2(t4[s][r] * CSC);
            ps[s][r] = (pg > qg) ? 0.f : e;
          }
      }

      ushort* pw = pbuf[wave] + lm * 64;
#pragma unroll
      for (int s = 0; s < 4; ++s) {
        uint2 pk;
        pk.x = (uint)f2bf(ps[s][0]) | ((uint)f2bf(ps[s][1]) << 16);
        pk.y = (uint)f2bf(ps[s][2]) | ((uint)f2bf(ps[s][3]) << 16);
        *(uint2*)(pw + ((((2 * s + (quad >> 1)) ^ psw) & 7) << 3) +
                  ((quad & 1) << 2)) = pk;
      }

      const ushort* vbuf = vt[it & 1];
      __builtin_amdgcn_s_setprio(1);
#pragma unroll
      for (int kc = 0; kc < 2; ++kc) {
        short8 pa = *(const short8*)(pw + ((((kc * 4 + quad) ^ psw) & 7) << 3));
        lacc = MFMA16(pa, vone, lacc);
#pragma unroll
        for (int c = 0; c < 4; ++c) {
          const int hrow = c * 16 + lm;
          const int fh = ((hrow >> 3) ^ hrow) & 7;
          short8 vb = *(const short8*)(
              vbuf + hrow * 64 + ((((4 * kc + quad) ^ fh) & 7) << 3));
          accz[c] = MFMA16(pa, vb, accz[c]);
        }
      }
      __builtin_amdgcn_s_setprio(0);

      if (more) {
        ushort* nbuf = vt[(it + 1) & 1];
        vt_write8(nbuf, h0, hsw, plb, nv0);
        vt_write8(nbuf, h0, hsw, plb + 32, nv1);
      }
    }

#pragma unroll
    for (int r = 0; r < 4; ++r) {
      const float inv = 1.f / lacc[r];
#pragma unroll
      for (int c = 0; c < 4; ++c)
        QKV[qcol + (size_t)(qrow + quad * 4 + r) * LD + c * 16 + lm] =
            f2bf(accz[c][r] * inv);
    }
  }
}

extern "C" void kernel_launch(void* const* d_in, const int* in_sizes, int n_in,
                              void* d_out, int out_size, void* d_ws, size_t ws_size,
                              hipStream_t stream) {
  (void)in_sizes; (void)n_in; (void)out_size; (void)ws_size;
  const float* x  = (const float*)d_in[0];   // (4,2048,1024) = (8192,1024)
  const float* wk = (const float*)d_in[1];   // (16,64,1024) flat (1024,1024)
  const float* wq = (const float*)d_in[2];
  const float* wv = (const float*)d_in[3];
  const float* wo = (const float*)d_in[4];   // (1024,1024)
  float* out = (float*)d_out;

  const size_t WSZ = (size_t)1024 * 1024;
  ushort* wqkv_b = (ushort*)d_ws;            // rows: 0..1023 Q, 1024.. K, 2048.. V
  ushort* wo_b = wqkv_b + 3 * WSZ;
  ushort* QKV = wo_b + WSZ;                  // 8192 x 3072
  ushort* xb = (ushort*)d_out;               // bf16 x in d_out (16 of 32 MB);
                                             // dead before out-proj writes

  // Fused converts: 4*(1M/4) + (8M/4) = 3145728 float4s = 12288 blocks exact.
  convert_all_kernel<<<12288, 256, 0, stream>>>(wq, wk, wv, wo, x,
                                                wqkv_b, wo_b, xb);

  // All-batch QKV projection: gemm8p (3-buf skeleton + fine phases).
  gemm8p_kernel<__hip_bfloat16><<<768, 512, 0, stream>>>(
      xb, 1024, wqkv_b, 1024, (__hip_bfloat16*)QKV, 3072, 1024);

  flash4_kernel<<<1024, 256, 0, stream>>>(QKV);

  // Out projection: Z (QKV cols 0..1023) * Wo^T -> fp32 out (gemm2p).
  gemm_kernel<float><<<512, 256, 0, stream>>>(
      QKV, 3072, wo_b, 1024, out, 1024, 1024, 1);
}